// Round 1
// baseline (442.319 us; speedup 1.0000x reference)
//
#include <hip/hip_runtime.h>

#define B_ 2
#define N_ 131072
#define K_ 20
#define E_ 256
#define TEMP_ 0.05f
#define SCORE_THR_ 0.04f

// ws layout (float offsets):
//   [0,40)        scoreSum[B][K]
//   [1024,11264)  xn  [B][K][E]
//   [16384,26624) sn  [B][K][E]
//   [32768, +B*K*N) mask [B][K][N]
#define WS_SCORE 0
#define WS_XN    1024
#define WS_SN    16384
#define WS_MASK  32768

__device__ inline float wave_sum(float v) {
    #pragma unroll
    for (int off = 32; off; off >>= 1) v += __shfl_xor(v, off, 64);
    return v;
}

// ---------------- Kernel A1: GEMM1 + GroupNorm + ReLU ----------------
// grid 8 = (b, group); 256 threads; thread -> (channel c = t>>2, k-quarter q = t&3)
__global__ __launch_bounds__(256) void kA1(const float* __restrict__ slots,
                                           const float* __restrict__ w1,
                                           const float* __restrict__ b1,
                                           const float* __restrict__ gn_g,
                                           const float* __restrict__ gn_b,
                                           float* __restrict__ ws) {
    __shared__ __align__(16) float slds[20 * 260];
    __shared__ float red[2];
    const int t = threadIdx.x;
    const int b = blockIdx.x >> 2, g = blockIdx.x & 3;
    // zero score accumulators (8 blocks x 5 = 40 values)
    if (t < 5) ws[WS_SCORE + blockIdx.x * 5 + t] = 0.f;
    if (t < 2) red[t] = 0.f;
    const float* sb = slots + (size_t)b * K_ * E_;
    #pragma unroll
    for (int i = 0; i < 20; ++i) slds[i * 260 + t] = sb[i * 256 + t];
    __syncthreads();

    const int c = t >> 2, q = t & 3;
    const int o = g * 64 + c;
    const float* w1r = w1 + (size_t)o * E_;
    float acc[5] = {0.f, 0.f, 0.f, 0.f, 0.f};
    for (int e4 = 0; e4 < 64; ++e4) {
        const float4 w4 = *(const float4*)(w1r + e4 * 4);
        #pragma unroll
        for (int kk = 0; kk < 5; ++kk) {
            const float4 s4 = *(const float4*)&slds[(q * 5 + kk) * 260 + e4 * 4];
            acc[kk] += w4.x * s4.x + w4.y * s4.y + w4.z * s4.z + w4.w * s4.w;
        }
    }
    const float bias = b1[o];
    float s1 = 0.f, s2 = 0.f;
    #pragma unroll
    for (int kk = 0; kk < 5; ++kk) {
        acc[kk] += bias;
        s1 += acc[kk];
        s2 += acc[kk] * acc[kk];
    }
    s1 = wave_sum(s1);
    s2 = wave_sum(s2);
    if ((t & 63) == 0) { atomicAdd(&red[0], s1); atomicAdd(&red[1], s2); }
    __syncthreads();
    const float mean = red[0] * (1.f / 1280.f);
    const float var  = red[1] * (1.f / 1280.f) - mean * mean;
    const float rstd = rsqrtf(var + 1e-5f);
    const float gg = gn_g[o], gb = gn_b[o];
    float* xn = ws + WS_XN + (size_t)b * K_ * E_;
    #pragma unroll
    for (int kk = 0; kk < 5; ++kk) {
        float v = (acc[kk] - mean) * rstd * gg + gb;
        v = v > 0.f ? v : 0.f;
        xn[(q * 5 + kk) * 256 + o] = v;   // layout [b][k][e]
    }
}

// ---------------- Kernel A2: GEMM2 + bias + L2-normalize over E ----------------
// grid 40 = (b, k); 256 threads; thread = output channel f
__global__ __launch_bounds__(256) void kA2(const float* __restrict__ w2,
                                           const float* __restrict__ b2,
                                           float* __restrict__ ws) {
    __shared__ __align__(16) float xv[256];
    __shared__ float wred[4];
    const int t = threadIdx.x;
    const int b = blockIdx.x / 20, k = blockIdx.x % 20;
    const float* xn = ws + WS_XN + (size_t)(b * 20 + k) * 256;
    xv[t] = xn[t];
    __syncthreads();
    const float* w2r = w2 + (size_t)t * 256;
    float acc = 0.f;
    for (int e4 = 0; e4 < 64; ++e4) {
        const float4 w4 = *(const float4*)(w2r + e4 * 4);
        const float4 x4 = *(const float4*)&xv[e4 * 4];
        acc += w4.x * x4.x + w4.y * x4.y + w4.z * x4.z + w4.w * x4.w;
    }
    acc += b2[t];
    float sq = wave_sum(acc * acc);
    if ((t & 63) == 0) wred[t >> 6] = sq;
    __syncthreads();
    const float nsq = wred[0] + wred[1] + wred[2] + wred[3];
    const float inv = 1.f / fmaxf(sqrtf(nsq), 1e-12f);
    ws[WS_SN + (size_t)(b * 20 + k) * 256 + t] = acc * inv;
}

// ---------------- Kernel B: logits + softmax + mask^T store + score sums ----------------
// grid 512 (256 blocks/batch, 512 points/block); 256 threads; 2 points/thread
__global__ __launch_bounds__(256) void kB(const float* __restrict__ feat,
                                          float* __restrict__ ws) {
    __shared__ __align__(16) float snl[5120];   // [k][e]
    __shared__ float wsum[4][20];
    const int t = threadIdx.x;
    const int b = blockIdx.x >> 8;
    const int n0 = (blockIdx.x & 255) * 512;
    const float* sng = ws + WS_SN + (size_t)b * 5120;
    #pragma unroll
    for (int i = 0; i < 20; ++i) snl[i * 256 + t] = sng[i * 256 + t];
    __syncthreads();

    const float* p0 = feat + ((size_t)b * N_ + n0 + t) * E_;
    const float* p1 = p0 + 256 * E_;
    float acc0[20], acc1[20];
    #pragma unroll
    for (int k = 0; k < 20; ++k) { acc0[k] = 0.f; acc1[k] = 0.f; }
    float nr0 = 0.f, nr1 = 0.f;

    // software pipeline, prefetch distance 2 (j-pairs)
    float4 a0 = *(const float4*)(p0);
    float4 a1 = *(const float4*)(p1);
    float4 b0 = *(const float4*)(p0 + 4);
    float4 b1v = *(const float4*)(p1 + 4);
    for (int j = 0; j < 64; j += 2) {
        const int jn = (j + 2 < 64) ? (j + 2) : 62;
        const float4 na0 = *(const float4*)(p0 + jn * 4);
        const float4 na1 = *(const float4*)(p1 + jn * 4);
        const float4 nb0 = *(const float4*)(p0 + jn * 4 + 4);
        const float4 nb1 = *(const float4*)(p1 + jn * 4 + 4);

        nr0 += a0.x * a0.x + a0.y * a0.y + a0.z * a0.z + a0.w * a0.w;
        nr1 += a1.x * a1.x + a1.y * a1.y + a1.z * a1.z + a1.w * a1.w;
        #pragma unroll
        for (int k = 0; k < 20; ++k) {
            const float4 s4 = *(const float4*)&snl[k * 256 + j * 4];
            acc0[k] += a0.x * s4.x + a0.y * s4.y + a0.z * s4.z + a0.w * s4.w;
            acc1[k] += a1.x * s4.x + a1.y * s4.y + a1.z * s4.z + a1.w * s4.w;
        }
        nr0 += b0.x * b0.x + b0.y * b0.y + b0.z * b0.z + b0.w * b0.w;
        nr1 += b1v.x * b1v.x + b1v.y * b1v.y + b1v.z * b1v.z + b1v.w * b1v.w;
        #pragma unroll
        for (int k = 0; k < 20; ++k) {
            const float4 s4 = *(const float4*)&snl[k * 256 + j * 4 + 4];
            acc0[k] += b0.x * s4.x + b0.y * s4.y + b0.z * s4.z + b0.w * s4.w;
            acc1[k] += b1v.x * s4.x + b1v.y * s4.y + b1v.z * s4.z + b1v.w * s4.w;
        }
        a0 = na0; a1 = na1; b0 = nb0; b1v = nb1;
    }

    // logits scale: 1/(||f||*TEMP)
    const float sc0 = rsqrtf(fmaxf(nr0, 1e-24f)) * (1.f / TEMP_);
    const float sc1 = rsqrtf(fmaxf(nr1, 1e-24f)) * (1.f / TEMP_);
    float m0 = -1e30f, m1 = -1e30f;
    #pragma unroll
    for (int k = 0; k < 20; ++k) {
        acc0[k] *= sc0; acc1[k] *= sc1;
        m0 = fmaxf(m0, acc0[k]); m1 = fmaxf(m1, acc1[k]);
    }
    float su0 = 0.f, su1 = 0.f;
    #pragma unroll
    for (int k = 0; k < 20; ++k) {
        acc0[k] = __expf(acc0[k] - m0); su0 += acc0[k];
        acc1[k] = __expf(acc1[k] - m1); su1 += acc1[k];
    }
    const float r0 = 1.f / su0, r1 = 1.f / su1;
    float* mg = ws + WS_MASK + (size_t)b * 20 * N_ + n0 + t;
    #pragma unroll
    for (int k = 0; k < 20; ++k) {
        const float v0 = acc0[k] * r0;
        const float v1 = acc1[k] * r1;
        mg[(size_t)k * N_] = v0;
        mg[(size_t)k * N_ + 256] = v1;
        acc0[k] = v0 + v1;  // local score contribution
    }
    // block score reduction
    #pragma unroll
    for (int k = 0; k < 20; ++k) acc0[k] = wave_sum(acc0[k]);
    const int wid = t >> 6, lid = t & 63;
    if (lid == 0) {
        #pragma unroll
        for (int k = 0; k < 20; ++k) wsum[wid][k] = acc0[k];
    }
    __syncthreads();
    if (t < 20) {
        const float s = wsum[0][t] + wsum[1][t] + wsum[2][t] + wsum[3][t];
        atomicAdd(&ws[WS_SCORE + b * 20 + t], s);
    }
}

// ---------------- Kernel D: rank/filter + gather kept columns + renormalize ----------------
// grid 1024 (512 blocks/batch); 256 threads; 1 point/thread
__global__ __launch_bounds__(256) void kD(const float* __restrict__ ws,
                                          float* __restrict__ out) {
    __shared__ float sc[20];
    __shared__ int rnk[20];
    __shared__ int src[20];
    __shared__ int nk_s;
    const int t = threadIdx.x;
    const int b = blockIdx.x >> 9;
    const int n = (blockIdx.x & 511) * 256 + t;
    if (t < 20) sc[t] = ws[WS_SCORE + b * 20 + t] * (1.f / (float)N_);
    if (t == 0) nk_s = 0;
    __syncthreads();
    if (t < 20) {
        const float mys = sc[t];
        int rank = 0;
        for (int j = 0; j < 20; ++j) {
            const float o = sc[j];
            rank += (o > mys) || (o == mys && j < t);
        }
        rnk[t] = rank;
    }
    __syncthreads();
    if (t < 20 && sc[t] >= SCORE_THR_) {
        int pos = 0;
        for (int j = 0; j < 20; ++j)
            pos += (sc[j] >= SCORE_THR_) && (rnk[j] < rnk[t]);
        src[pos] = t;
        atomicAdd(&nk_s, 1);
    }
    __syncthreads();
    const int nk = nk_s;
    const float* mg = ws + WS_MASK + (size_t)b * 20 * N_;
    float mv[20];
    float den = 1e-8f;
    #pragma unroll
    for (int p = 0; p < 20; ++p) {
        float v = 0.f;
        if (p < nk) v = mg[(size_t)src[p] * N_ + n];
        mv[p] = v;
        den += v;
    }
    const float r = 1.f / den;
    float* og = out + (size_t)b * 20 * N_ + n;
    #pragma unroll
    for (int p = 0; p < 20; ++p) og[(size_t)p * N_] = (p < nk) ? mv[p] * r : 0.f;
}

extern "C" void kernel_launch(void* const* d_in, const int* in_sizes, int n_in,
                              void* d_out, int out_size, void* d_ws, size_t ws_size,
                              hipStream_t stream) {
    const float* feat  = (const float*)d_in[0];
    const float* slots = (const float*)d_in[1];
    const float* w1    = (const float*)d_in[2];
    const float* b1    = (const float*)d_in[3];
    const float* gng   = (const float*)d_in[4];
    const float* gnb   = (const float*)d_in[5];
    const float* w2    = (const float*)d_in[6];
    const float* b2    = (const float*)d_in[7];
    float* ws  = (float*)d_ws;
    float* out = (float*)d_out;

    kA1<<<8,    256, 0, stream>>>(slots, w1, b1, gng, gnb, ws);
    kA2<<<40,   256, 0, stream>>>(w2, b2, ws);
    kB <<<512,  256, 0, stream>>>(feat, ws);
    kD <<<1024, 256, 0, stream>>>(ws, out);
}

// Round 2
// 431.850 us; speedup vs baseline: 1.0242x; 1.0242x over previous
//
#include <hip/hip_runtime.h>

#define B_ 2
#define N_ 131072
#define K_ 20
#define E_ 256
#define TEMP_ 0.05f
#define SCORE_THR_ 0.04f

// ws layout (float offsets):
//   [0,40)              score[B][K]   (final mean scores, written by kC)
//   [1024,11264)        xn [B][K][E]
//   [16384,26624)       sn [B][K][E]
//   [32768,+B*K*N)      mask [B][K][N]            (ends at 5275648)
//   [6291456,+1024*20)  score partials per kB block
#define WS_SCORE 0
#define WS_XN    1024
#define WS_SN    16384
#define WS_MASK  32768
#define WS_SPART 6291456

__device__ inline float wave_sum(float v) {
    #pragma unroll
    for (int off = 32; off; off >>= 1) v += __shfl_xor(v, off, 64);
    return v;
}

// ---------------- Kernel A1: GEMM1 + GroupNorm + ReLU ----------------
__global__ __launch_bounds__(256) void kA1(const float* __restrict__ slots,
                                           const float* __restrict__ w1,
                                           const float* __restrict__ b1,
                                           const float* __restrict__ gn_g,
                                           const float* __restrict__ gn_b,
                                           float* __restrict__ ws) {
    __shared__ __align__(16) float slds[20 * 260];
    __shared__ float red[2];
    const int t = threadIdx.x;
    const int b = blockIdx.x >> 2, g = blockIdx.x & 3;
    if (t < 2) red[t] = 0.f;
    const float* sb = slots + (size_t)b * K_ * E_;
    #pragma unroll
    for (int i = 0; i < 20; ++i) slds[i * 260 + t] = sb[i * 256 + t];
    __syncthreads();

    const int c = t >> 2, q = t & 3;
    const int o = g * 64 + c;
    const float* w1r = w1 + (size_t)o * E_;
    float acc[5] = {0.f, 0.f, 0.f, 0.f, 0.f};
    for (int e4 = 0; e4 < 64; ++e4) {
        const float4 w4 = *(const float4*)(w1r + e4 * 4);
        #pragma unroll
        for (int kk = 0; kk < 5; ++kk) {
            const float4 s4 = *(const float4*)&slds[(q * 5 + kk) * 260 + e4 * 4];
            acc[kk] += w4.x * s4.x + w4.y * s4.y + w4.z * s4.z + w4.w * s4.w;
        }
    }
    const float bias = b1[o];
    float s1 = 0.f, s2 = 0.f;
    #pragma unroll
    for (int kk = 0; kk < 5; ++kk) {
        acc[kk] += bias;
        s1 += acc[kk];
        s2 += acc[kk] * acc[kk];
    }
    s1 = wave_sum(s1);
    s2 = wave_sum(s2);
    if ((t & 63) == 0) { atomicAdd(&red[0], s1); atomicAdd(&red[1], s2); }
    __syncthreads();
    const float mean = red[0] * (1.f / 1280.f);
    const float var  = red[1] * (1.f / 1280.f) - mean * mean;
    const float rstd = rsqrtf(var + 1e-5f);
    const float gg = gn_g[o], gb = gn_b[o];
    float* xn = ws + WS_XN + (size_t)b * K_ * E_;
    #pragma unroll
    for (int kk = 0; kk < 5; ++kk) {
        float v = (acc[kk] - mean) * rstd * gg + gb;
        v = v > 0.f ? v : 0.f;
        xn[(q * 5 + kk) * 256 + o] = v;
    }
}

// ---------------- Kernel A2: GEMM2 + bias + L2-normalize over E ----------------
__global__ __launch_bounds__(256) void kA2(const float* __restrict__ w2,
                                           const float* __restrict__ b2,
                                           float* __restrict__ ws) {
    __shared__ __align__(16) float xv[256];
    __shared__ float wred[4];
    const int t = threadIdx.x;
    const int b = blockIdx.x / 20, k = blockIdx.x % 20;
    const float* xn = ws + WS_XN + (size_t)(b * 20 + k) * 256;
    xv[t] = xn[t];
    __syncthreads();
    const float* w2r = w2 + (size_t)t * 256;
    float acc = 0.f;
    for (int e4 = 0; e4 < 64; ++e4) {
        const float4 w4 = *(const float4*)(w2r + e4 * 4);
        const float4 x4 = *(const float4*)&xv[e4 * 4];
        acc += w4.x * x4.x + w4.y * x4.y + w4.z * x4.z + w4.w * x4.w;
    }
    acc += b2[t];
    float sq = wave_sum(acc * acc);
    if ((t & 63) == 0) wred[t >> 6] = sq;
    __syncthreads();
    const float nsq = wred[0] + wred[1] + wred[2] + wred[3];
    const float inv = 1.f / fmaxf(sqrtf(nsq), 1e-12f);
    ws[WS_SN + (size_t)(b * 20 + k) * 256 + t] = acc * inv;
}

// ---------------- Kernel B v2: LDS-staged coalesced logits+softmax ----------------
// grid 1024 (512 blocks/batch, 256 points/block); 256 threads
// per chunk: 32 points staged (32KB contiguous global -> LDS), 8 threads/point
__global__ __launch_bounds__(256, 2) void kB(const float* __restrict__ feat,
                                             float* __restrict__ ws) {
    __shared__ __align__(16) float snl[20 * 260];
    __shared__ __align__(16) float fl[32 * 260];
    __shared__ float pl[640];          // [k][32] prob staging
    __shared__ float wsum[4][20];
    const int t = threadIdx.x;
    const int b = blockIdx.x >> 9;
    const int n0 = (blockIdx.x & 511) << 8;
    const float* sng = ws + WS_SN + (size_t)b * 5120;
    #pragma unroll
    for (int i = 0; i < 20; ++i) snl[i * 260 + t] = sng[i * 256 + t];
    const int p = t >> 3, s = t & 7;
    const int lane = t & 63, w = t >> 6;
    float sreg0 = 0.f, sreg1 = 0.f, sreg2 = 0.f;
    const float4* gbase = (const float4*)(feat + ((size_t)b * N_ + n0) * E_);
    float* mgbase = ws + WS_MASK + (size_t)b * 20 * N_ + n0;
    __syncthreads();

    for (int c = 0; c < 8; ++c) {
        // ---- stage 32 points (perfectly coalesced: contiguous 32 KB) ----
        const float4* g4 = gbase + (size_t)c * 2048;
        #pragma unroll
        for (int i = 0; i < 8; ++i) {
            const int idx = t + (i << 8);
            const float4 v = g4[idx];
            const int pp = idx >> 6, cc = idx & 63;
            *(float4*)&fl[pp * 260 + (cc << 2)] = v;
        }
        __syncthreads();
        // ---- compute: thread (p,s) covers e in {4s+32j+r} ----
        float acc[20];
        float nr = 0.f;
        #pragma unroll
        for (int k = 0; k < 20; ++k) acc[k] = 0.f;
        const float* frow = &fl[p * 260];
        #pragma unroll
        for (int j = 0; j < 8; ++j) {
            const int col = (s << 2) + (j << 5);
            const float4 f4 = *(const float4*)&frow[col];
            nr += f4.x * f4.x + f4.y * f4.y + f4.z * f4.z + f4.w * f4.w;
            #pragma unroll
            for (int k = 0; k < 20; ++k) {
                const float4 s4 = *(const float4*)&snl[k * 260 + col];
                acc[k] += f4.x * s4.x + f4.y * s4.y + f4.z * s4.z + f4.w * s4.w;
            }
        }
        // ---- reduce over 8 slices (lanes 8p..8p+7) ----
        #pragma unroll
        for (int off = 1; off < 8; off <<= 1) {
            nr += __shfl_xor(nr, off, 64);
            #pragma unroll
            for (int k = 0; k < 20; ++k) acc[k] += __shfl_xor(acc[k], off, 64);
        }
        // ---- softmax (redundant in all 8 lanes of a point-group) ----
        const float scl = rsqrtf(fmaxf(nr, 1e-24f)) * (1.f / TEMP_);
        float m = -1e30f;
        #pragma unroll
        for (int k = 0; k < 20; ++k) { acc[k] *= scl; m = fmaxf(m, acc[k]); }
        float su = 0.f;
        #pragma unroll
        for (int k = 0; k < 20; ++k) { acc[k] = __expf(acc[k] - m); su += acc[k]; }
        const float r = 1.f / su;
        // lane s owns k = s, s+8, s+16 (select without runtime indexing)
        float v0 = 0.f, v1 = 0.f, v2 = 0.f;
        #pragma unroll
        for (int k = 0; k < 8; ++k) {
            if (s == k) {
                v0 = acc[k] * r;
                v1 = acc[k + 8] * r;
                v2 = (k < 4) ? acc[k + 16] * r : 0.f;
            }
        }
        pl[(s << 5) + p] = v0;
        pl[((s + 8) << 5) + p] = v1;
        if (s < 4) pl[((s + 16) << 5) + p] = v2;
        sreg0 += v0; sreg1 += v1; sreg2 += v2;
        __syncthreads();
        // ---- coalesced store of 640 probs ----
        #pragma unroll
        for (int i = 0; i < 3; ++i) {
            const int idx = t + (i << 8);
            if (idx < 640) {
                const int k = idx >> 5, pp = idx & 31;
                mgbase[(size_t)k * N_ + (c << 5) + pp] = pl[idx];
            }
        }
        __syncthreads();   // pl/fl reusable next chunk
    }
    // ---- per-block score partials (reduce over p: xor 8,16,32) ----
    #pragma unroll
    for (int off = 8; off < 64; off <<= 1) {
        sreg0 += __shfl_xor(sreg0, off, 64);
        sreg1 += __shfl_xor(sreg1, off, 64);
        sreg2 += __shfl_xor(sreg2, off, 64);
    }
    if (lane < 8) {
        wsum[w][lane] = sreg0;
        wsum[w][lane + 8] = sreg1;
        if (lane < 4) wsum[w][lane + 16] = sreg2;
    }
    __syncthreads();
    if (t < 20) {
        const float sum = wsum[0][t] + wsum[1][t] + wsum[2][t] + wsum[3][t];
        ws[WS_SPART + (size_t)blockIdx.x * 20 + t] = sum;
    }
}

// ---------------- Kernel C: reduce score partials ----------------
// grid 40 = (b,k); 64 threads
__global__ __launch_bounds__(64) void kC(float* __restrict__ ws) {
    const int l = threadIdx.x;
    const int b = blockIdx.x / 20, k = blockIdx.x % 20;
    const float* sp = ws + WS_SPART;
    float sum = 0.f;
    #pragma unroll
    for (int i = 0; i < 8; ++i)
        sum += sp[(size_t)(b * 512 + l + i * 64) * 20 + k];
    sum = wave_sum(sum);
    if (l == 0) ws[WS_SCORE + blockIdx.x] = sum * (1.f / (float)N_);
}

// ---------------- Kernel D: rank/filter + gather + renormalize ----------------
__global__ __launch_bounds__(256) void kD(const float* __restrict__ ws,
                                          float* __restrict__ out) {
    __shared__ float sc[20];
    __shared__ int rnk[20];
    __shared__ int src[20];
    __shared__ int nk_s;
    const int t = threadIdx.x;
    const int b = blockIdx.x >> 9;
    const int n = (blockIdx.x & 511) * 256 + t;
    if (t < 20) sc[t] = ws[WS_SCORE + b * 20 + t];
    if (t == 0) nk_s = 0;
    __syncthreads();
    if (t < 20) {
        const float mys = sc[t];
        int rank = 0;
        for (int j = 0; j < 20; ++j) {
            const float o = sc[j];
            rank += (o > mys) || (o == mys && j < t);
        }
        rnk[t] = rank;
    }
    __syncthreads();
    if (t < 20 && sc[t] >= SCORE_THR_) {
        int pos = 0;
        for (int j = 0; j < 20; ++j)
            pos += (sc[j] >= SCORE_THR_) && (rnk[j] < rnk[t]);
        src[pos] = t;
        atomicAdd(&nk_s, 1);
    }
    __syncthreads();
    const int nk = nk_s;
    const float* mg = ws + WS_MASK + (size_t)b * 20 * N_;
    float mv[20];
    float den = 1e-8f;
    #pragma unroll
    for (int p = 0; p < 20; ++p) {
        float v = 0.f;
        if (p < nk) v = mg[(size_t)src[p] * N_ + n];
        mv[p] = v;
        den += v;
    }
    const float r = 1.f / den;
    float* og = out + (size_t)b * 20 * N_ + n;
    #pragma unroll
    for (int p = 0; p < 20; ++p) og[(size_t)p * N_] = (p < nk) ? mv[p] * r : 0.f;
}

extern "C" void kernel_launch(void* const* d_in, const int* in_sizes, int n_in,
                              void* d_out, int out_size, void* d_ws, size_t ws_size,
                              hipStream_t stream) {
    const float* feat  = (const float*)d_in[0];
    const float* slots = (const float*)d_in[1];
    const float* w1    = (const float*)d_in[2];
    const float* b1    = (const float*)d_in[3];
    const float* gng   = (const float*)d_in[4];
    const float* gnb   = (const float*)d_in[5];
    const float* w2    = (const float*)d_in[6];
    const float* b2    = (const float*)d_in[7];
    float* ws  = (float*)d_ws;
    float* out = (float*)d_out;

    kA1<<<8,    256, 0, stream>>>(slots, w1, b1, gng, gnb, ws);
    kA2<<<40,   256, 0, stream>>>(w2, b2, ws);
    kB <<<1024, 256, 0, stream>>>(feat, ws);
    kC <<<40,   64,  0, stream>>>(ws);
    kD <<<1024, 256, 0, stream>>>(ws, out);
}